// Round 11
// baseline (462.249 us; speedup 1.0000x reference)
//
#include <hip/hip_runtime.h>
#include <math.h>

#define LL 256
#define DD 64

typedef __attribute__((ext_vector_type(8))) short bf16x8;
typedef __attribute__((ext_vector_type(4))) float f32x4;

static __device__ __forceinline__ unsigned short f2bf(float f) {
    union { float f; unsigned u; } v; v.f = f;
    unsigned r = v.u + 0x7fffu + ((v.u >> 16) & 1u);
    return (unsigned short)(r >> 16);
}
static __device__ __forceinline__ float bf2f(unsigned short h) {
    union { unsigned u; float f; } v; v.u = ((unsigned)h) << 16;
    return v.f;
}

// 4 blocks per group (row-quarters), 256 thr = 4 waves, wave owns 16 rows x 256 cols.
// acc[16] f32x4 = 64 regs -> combined VGPR+AGPR ~112 <= 128 -> 4 waves/SIMD.
// (Round-7 lesson: acc[2][16]=128 AGPR + 124 VGPR = 252 -> 2 waves/SIMD -> 8 waves/CU
//  -> latency-bound at ~92us with every pipe <25% busy.)
// k is NOT staged in LDS: each wave converts k fragments from L2-hot fp32 on the fly.
// Group scalars (theta, GEMV, th_sc) recomputed per sibling block - deterministic,
// bit-identical across siblings.
__launch_bounds__(256, 4)
__global__ void fused_attn_v8(const float* __restrict__ q,
                              const float* __restrict__ k,
                              const float* __restrict__ Wq,
                              const float* __restrict__ bq,
                              const float* __restrict__ Wk,
                              const float* __restrict__ bk,
                              const float* __restrict__ W1,
                              const float* __restrict__ W2a,
                              const float* __restrict__ W2b,
                              float* __restrict__ out,
                              int ngroup)
{
    __shared__ float sPq[256];      // -> sSq after += bq0
    __shared__ float sPk[256];      // -> sSk after += bk0
    __shared__ float sPqk[256];     // q_i . k_i
    __shared__ float sTh[256];      // theta vector
    __shared__ float kwred[4][64];
    __shared__ float kw_s[64];
    __shared__ float sRed[4];

    const int tid  = threadIdx.x;
    const int lane = tid & 63;
    const int w    = tid >> 6;      // wave 0..3
    const int r16  = lane & 15;
    const int g4   = lane >> 4;

    const int bid  = blockIdx.x;
    const int gidx = bid % ngroup;  // siblings at stride ngroup=512 (512%8==0 -> same XCD)
    const int rb   = bid / ngroup;  // row-quarter 0..3
    const int row0 = rb * 64 + w * 16;

    const size_t gbase = (size_t)gidx * (LL * DD);
    const float* qg = q + gbase;
    const float* kg = k + gbase;
    const float4* q4 = (const float4*)qg;
    const float4* k4 = (const float4*)kg;

    // ---- A-operand (q) fragment loads for this wave's 16 rows, issued first ----
    float4 aq[2][2];                 // [kk][half]
#pragma unroll
    for (int kk = 0; kk < 2; ++kk) {
        const float* p = qg + (row0 + r16) * DD + kk * 32 + g4 * 8;
        aq[kk][0] = ((const float4*)p)[0];
        aq[kk][1] = ((const float4*)p)[1];
    }

    // ---- phase 1: per-row dots, one row per thread (all 256 rows) ----
    {
        const float4* wq4 = (const float4*)Wq;
        const float4* wk4 = (const float4*)Wk;
        float pq = 0.f, pk = 0.f, pqk = 0.f;
#pragma unroll
        for (int it = 0; it < 16; ++it) {
            const float4 vq = q4[tid * 16 + it];
            const float4 vk = k4[tid * 16 + it];
            const float4 a = wq4[it];
            const float4 b = wk4[it];
            pq  += vq.x * a.x + vq.y * a.y + vq.z * a.z + vq.w * a.w;
            pk  += vk.x * b.x + vk.y * b.y + vk.z * b.z + vk.w * b.w;
            pqk += vq.x * vk.x + vq.y * vk.y + vq.z * vk.z + vq.w * vk.w;
        }
        sPq[tid] = pq; sPk[tid] = pk; sPqk[tid] = pqk;
    }

    // ---- phase 1b: kw[d] = sum_j W1[j] * k[j][d] (dim-major, coalesced) ----
    {
        const int dd = tid & 63, jc = tid >> 6;
        float s = 0.f;
#pragma unroll 8
        for (int j = jc * 64; j < jc * 64 + 64; ++j)
            s += W1[j] * kg[j * DD + dd];
        kwred[jc][dd] = s;
    }
    __syncthreads();                                   // B1
    if (tid < 64)
        kw_s[tid] = kwred[0][tid] + kwred[1][tid] + kwred[2][tid] + kwred[3][tid];
    __syncthreads();                                   // B2

    // ---- theta + Sigma (one row per thread) ----
    {
        const float bq0 = bq[0], bk0 = bk[0];
        const float4* kw4 = (const float4*)kw_s;
        float s = 0.f;
#pragma unroll
        for (int it = 0; it < 16; ++it) {
            const float4 vq = q4[tid * 16 + it];       // L1/L2-hot re-read
            const float4 kv = kw4[it];
            s += vq.x * kv.x + vq.y * kv.y + vq.z * kv.z + vq.w * kv.w;
        }
        sTh[tid] = s - W1[tid] * sPqk[tid];
        sPq[tid] += bq0;                               // sSq
        sPk[tid] += bk0;                               // sSk
    }
    __syncthreads();                                   // B3

    // ---- GEMV: hdn = W2a @ theta, leaky(0.1), dot W2b -> th_sc ----
    {
        const float4* wrow = (const float4*)(W2a + tid * LL);
        const float4* th4  = (const float4*)sTh;
        float h = 0.f;
#pragma unroll 8
        for (int c = 0; c < 64; ++c) {
            const float4 wv = wrow[c];
            const float4 tv = th4[c];
            h += wv.x * tv.x + wv.y * tv.y + wv.z * tv.z + wv.w * tv.w;
        }
        const float hl = (h >= 0.f) ? h : 0.1f * h;
        float contrib = hl * W2b[tid];
#pragma unroll
        for (int m = 1; m < 64; m <<= 1) contrib += __shfl_xor(contrib, m);
        if (lane == 0) sRed[w] = contrib;
    }
    __syncthreads();                                   // B4 (last barrier)
    const float th_sc = sRed[0] + sRed[1] + sRed[2] + sRed[3];

    // ---- convert A frags to bf16 hi/lo ----
    bf16x8 qhi[2], qlo[2];
#pragma unroll
    for (int kk = 0; kk < 2; ++kk) {
        const float fv[8] = {aq[kk][0].x, aq[kk][0].y, aq[kk][0].z, aq[kk][0].w,
                             aq[kk][1].x, aq[kk][1].y, aq[kk][1].z, aq[kk][1].w};
#pragma unroll
        for (int e = 0; e < 8; ++e) {
            const unsigned short h = f2bf(fv[e]);
            qhi[kk][e] = (short)h;
            qlo[kk][e] = (short)f2bf(fv[e] - bf2f(h));
        }
    }

    // ---- main: sim rows [row0,row0+16) x all 256 cols, 3-term bf16-split MFMA ----
    f32x4 acc[16];
#pragma unroll
    for (int ct = 0; ct < 16; ++ct) acc[ct] = (f32x4){0.f, 0.f, 0.f, 0.f};

#pragma unroll 4
    for (int ct = 0; ct < 16; ++ct) {
        const float* kp = kg + (ct * 16 + r16) * DD + g4 * 8;
        f32x4 c = acc[ct];
#pragma unroll
        for (int kk = 0; kk < 2; ++kk) {
            const float4 a = ((const float4*)(kp + kk * 32))[0];
            const float4 b = ((const float4*)(kp + kk * 32))[1];
            const float fv[8] = {a.x, a.y, a.z, a.w, b.x, b.y, b.z, b.w};
            bf16x8 bh, bl;
#pragma unroll
            for (int e = 0; e < 8; ++e) {
                const unsigned short h = f2bf(fv[e]);
                bh[e] = (short)h;
                bl[e] = (short)f2bf(fv[e] - bf2f(h));
            }
            c = __builtin_amdgcn_mfma_f32_16x16x32_bf16(qhi[kk], bh, c, 0, 0, 0);
            c = __builtin_amdgcn_mfma_f32_16x16x32_bf16(qhi[kk], bl, c, 0, 0, 0);
            c = __builtin_amdgcn_mfma_f32_16x16x32_bf16(qlo[kk], bh, c, 0, 0, 0);
        }
        acc[ct] = c;
    }

    // ---- epilogue: logits, row softmax (unmasked denom), threshold, store ----
    float skv[16];
#pragma unroll
    for (int ct = 0; ct < 16; ++ct) skv[ct] = sPk[ct * 16 + r16];   // sSk

    float* og = out + (size_t)gidx * (LL * LL);
#pragma unroll
    for (int r = 0; r < 4; ++r) {
        const int row = row0 + g4 * 4 + r;             // C/D: row=(lane>>4)*4+reg
        const float sq = sPq[row];                     // sSq
        float lg[16];
        float mx = -INFINITY;
#pragma unroll
        for (int ct = 0; ct < 16; ++ct) {
            lg[ct] = acc[ct][r] * sq * skv[ct];
            mx = fmaxf(mx, lg[ct]);
        }
        mx = fmaxf(mx, __shfl_xor(mx, 1));
        mx = fmaxf(mx, __shfl_xor(mx, 2));
        mx = fmaxf(mx, __shfl_xor(mx, 4));
        mx = fmaxf(mx, __shfl_xor(mx, 8));
        float sum = 0.f;
#pragma unroll
        for (int ct = 0; ct < 16; ++ct) {
            const float pe = __expf(lg[ct] - mx);
            sum += pe;                                 // unmasked denominator
            lg[ct] = (lg[ct] > th_sc) ? pe : 0.f;      // masked numerator
        }
        sum += __shfl_xor(sum, 1);
        sum += __shfl_xor(sum, 2);
        sum += __shfl_xor(sum, 4);
        sum += __shfl_xor(sum, 8);
        const float rinv = 1.0f / sum;
#pragma unroll
        for (int ct = 0; ct < 16; ++ct)
            og[row * LL + ct * 16 + r16] = lg[ct] * rinv;
    }
}

extern "C" void kernel_launch(void* const* d_in, const int* in_sizes, int n_in,
                              void* d_out, int out_size, void* d_ws, size_t ws_size,
                              hipStream_t stream) {
    const float* q   = (const float*)d_in[0];
    const float* k   = (const float*)d_in[1];
    const float* Wq  = (const float*)d_in[2];
    const float* bq  = (const float*)d_in[3];
    const float* Wk  = (const float*)d_in[4];
    const float* bk  = (const float*)d_in[5];
    const float* W1  = (const float*)d_in[6];
    const float* W2a = (const float*)d_in[7];
    const float* W2b = (const float*)d_in[8];
    float* out = (float*)d_out;

    const int ngroup = in_sizes[0] / (LL * DD);        // 512
    fused_attn_v8<<<dim3(ngroup * 4), dim3(256), 0, stream>>>(
        q, k, Wq, bq, Wk, bk, W1, W2a, W2b, out, ngroup);
}